// Round 1
// baseline (274.761 us; speedup 1.0000x reference)
//
#include <hip/hip_runtime.h>

#define SEQ 4096
#define DM 1024
#define DS 64
#define KS 64
#define R 16   // outputs per thread along t

// ---------------------------------------------------------------------------
// Kernel 1: csum[d] = sum_m C[m, d]   (C is [DM, DS] row-major)
// grid 16 blocks x 256 threads; block b covers m in [b*64, b*64+64)
// ---------------------------------------------------------------------------
__global__ void csum_kernel(const float* __restrict__ C, float* __restrict__ csum) {
    int d    = threadIdx.x & 63;
    int mloc = threadIdx.x >> 6;           // 0..3
    int m0   = blockIdx.x * 64;
    float s = 0.f;
#pragma unroll
    for (int j = 0; j < 16; ++j) {
        int m = m0 + j * 4 + mloc;
        s += C[m * DS + d];
    }
    __shared__ float red[4][64];
    red[mloc][d] = s;
    __syncthreads();
    if (threadIdx.x < 64) {
        float t = red[0][d] + red[1][d] + red[2][d] + red[3][d];
        atomicAdd(&csum[d], t);
    }
}

// ---------------------------------------------------------------------------
// Kernel 2: Kt[k*64 + l] = sum_d csum[d] * exp(A[d]*dt[k]*l) * B[d, k]
// one wave per k (lanes = l), 65536 threads total
// ---------------------------------------------------------------------------
__global__ void taps_kernel(const float* __restrict__ A, const float* __restrict__ B,
                            const float* __restrict__ log_dt,
                            const float* __restrict__ csum, float* __restrict__ Kt) {
    int g = blockIdx.x * blockDim.x + threadIdx.x;   // 0 .. 65535
    int l = g & 63;
    int k = g >> 6;
    float dt = __expf(log_dt[k]);
    float fl = (float)l;
    float acc = 0.f;
#pragma unroll 8
    for (int d = 0; d < DS; ++d) {
        acc += csum[d] * __expf(A[d] * dt * fl) * B[d * DM + k];
    }
    Kt[k * KS + l] = acc;
}

// ---------------------------------------------------------------------------
// Kernel 3: main depthwise conv.
// y[b,t,k] = D[k]*u[b,t,k] + sum_l Kt[k,l]*u[b, t+31-l, k]
// Block: 256 threads = 4 waves; lane = channel (64 channels per block),
// wave wv handles t in [t0 + wv*R, t0 + wv*R + R). Block tile: 64 k x 64 t.
// ---------------------------------------------------------------------------
__global__ __launch_bounds__(256)
void conv_kernel(const float* __restrict__ u, const float* __restrict__ Kt,
                 const float* __restrict__ D, float* __restrict__ y) {
    __shared__ float taps[64 * 65];        // +1 pad: (k+l)%32 banks -> 2-way (free)

    int k0 = blockIdx.x * 64;
    int t0 = blockIdx.y * 64;
    int b  = blockIdx.z;

    // stage this block's 64 channels' taps into LDS
    for (int i = threadIdx.x; i < 64 * 64; i += 256) {
        int kk = i >> 6, l = i & 63;
        taps[kk * 65 + l] = Kt[(k0 + kk) * KS + l];
    }
    __syncthreads();

    int kl = threadIdx.x & 63;
    int wv = threadIdx.x >> 6;
    int ts = t0 + wv * R;

    const float* up = u + (size_t)b * SEQ * DM + k0 + kl;

    // register window: w[i] = u[b, ts-32+i, k]   i in [0, R+63)
    float w[R + 63];
    int tw0 = ts - 32;
#pragma unroll
    for (int i = 0; i < R + 63; ++i) {
        int t = tw0 + i;                   // wave-uniform condition
        w[i] = (t >= 0 && t < SEQ) ? up[(size_t)t * DM] : 0.f;
    }

    float acc[R];
#pragma unroll
    for (int r = 0; r < R; ++r) acc[r] = 0.f;

#pragma unroll
    for (int l = 0; l < 64; ++l) {
        float tap = taps[kl * 65 + l];
#pragma unroll
        for (int r = 0; r < R; ++r)
            acc[r] = fmaf(tap, w[r + 63 - l], acc[r]);
    }

    float Dk = D[k0 + kl];
    float* yp = y + ((size_t)b * SEQ + ts) * DM + k0 + kl;
#pragma unroll
    for (int r = 0; r < R; ++r)
        yp[(size_t)r * DM] = fmaf(Dk, w[r + 32], acc[r]);
}

// ---------------------------------------------------------------------------
extern "C" void kernel_launch(void* const* d_in, const int* in_sizes, int n_in,
                              void* d_out, int out_size, void* d_ws, size_t ws_size,
                              hipStream_t stream) {
    const float* u      = (const float*)d_in[0];
    const float* A      = (const float*)d_in[1];
    const float* Bp     = (const float*)d_in[2];
    const float* Cp     = (const float*)d_in[3];
    const float* Dp     = (const float*)d_in[4];
    const float* log_dt = (const float*)d_in[5];
    float* y = (float*)d_out;

    float* csum = (float*)d_ws;            // 64 floats
    float* Kt   = csum + 64;               // 65536 floats

    hipMemsetAsync(csum, 0, DS * sizeof(float), stream);
    csum_kernel<<<16, 256, 0, stream>>>(Cp, csum);
    taps_kernel<<<(DM * KS) / 256, 256, 0, stream>>>(A, Bp, log_dt, csum, Kt);

    dim3 grid(DM / 64, SEQ / 64, 8);
    conv_kernel<<<grid, 256, 0, stream>>>(u, Kt, Dp, y);
}